// Round 17
// baseline (102.235 us; speedup 1.0000x reference)
//
#include <hip/hip_runtime.h>

#define MDIM 512
#define LCH  31
#define CDIM 542   // MD + L - 1
#define INW  1024
#define RS   (INW*LCH)          // floats per input row = 31744
#define NELEM (MDIM*MDIM*LCH)   // 8126464
#define GB3  2048               // k3/k4 grid blocks

#define TNK  8                  // output n-cols per k1 tile (1 wave per tile)
#define NT   64                 // tiles per row (512/8)
#define NPAIR 256               // m-pairs
#define SEGF 560                // staged floats per sub-tile (18 cols x 31 + pad)
#define NF4  140                // float4s per sub-tile
#define DIAG 38                 // distinct c per tile: TNK + LCH - 1

// ws layout (floats): part[pair][tile][mm][128], yn, pmaxY[512], pmaxT[GB3], scl[2]
#define PART_OFF 0
#define PART_SZ  (NPAIR*NT*2*128)        // 4194304 (16.8 MB)
#define YN_OFF   (PART_OFF + PART_SZ)
#define PMY_OFF  (YN_OFF + MDIM*CDIM)
#define PMT_OFF  (PMY_OFF + MDIM)
#define SCL_OFF  (PMT_OFF + GB3)

// K1: barrier-free single-wave blocks. One wave owns one (m-pair, n-tile of
// 8); 6.6 KB LDS -> 24 independent blocks/CU, each a free-running
// load->compute pipeline with NO __syncthreads (within a wave, LDS ops
// complete in program order; compiler inserts lgkmcnt waits;
// wave_barrier() is a zero-cost scheduling fence). r9->r16 showed per-CU
// BW scales with the number of independently-staggered units (8 ganged
// 4-wave blocks = 13 GB/s/CU); this maximizes them. Clamped values only
// meet zero weights:
//   col -1 / 1024 -> wx0/wx3 = 0 at n = 0/511
//   row -1 / 1024 -> wa0/wb3 = 0 at m = 0/511
__global__ __launch_bounds__(64) void k1_fused(const float* __restrict__ X,
                                               const float* __restrict__ H,
                                               float* __restrict__ part) {
    __shared__ float xv[2][SEGF];     // 4.5 KB vertically-resized tiles
    __shared__ float xm[2][TNK][33];  // 2.1 KB H*conv tiles, padded

    const int bid  = blockIdx.x;
    const int t    = bid & (NT-1);
    const int p    = bid >> 6;
    const int n0   = t * TNK;
    const int m0   = 2*p;
    const int lane = threadIdx.x;
    const int qa   = 496*t - 32;      // float4-aligned staged-q origin

    const float* rp0 = X + (size_t)max(4*p - 1, 0) * RS;
    const float* rp1 = X + (size_t)(4*p    ) * RS;
    const float* rp2 = X + (size_t)(4*p + 1) * RS;
    const float* rp3 = X + (size_t)(4*p + 2) * RS;
    const float* rp4 = X + (size_t)(4*p + 3) * RS;
    const float* rp5 = X + (size_t)min(4*p + 4, INW-1) * RS;

    float wa0=0.125f, wa1=0.375f, wa2=0.375f, wa3=0.125f;   // m = m0
    if (m0 == 0) {
        const float s = 1.0f/0.875f;
        wa0 = 0.f; wa1 = 0.375f*s; wa2 = 0.375f*s; wa3 = 0.125f*s;
    }
    float wb0=0.125f, wb1=0.375f, wb2=0.375f, wb3=0.125f;   // m = m0+1
    if (m0 + 1 == MDIM-1) {
        const float s = 1.0f/0.875f;
        wb0 = 0.125f*s; wb1 = 0.375f*s; wb2 = 0.375f*s; wb3 = 0.f;
    }

    // ---- phase 1: 6-row streams, vertical 4-tap for both m ----
    for (int u = lane; u < NF4; u += 64) {
        int q = qa + 4*u;
        q = min(max(q, 0), RS - 4);   // clamp -> zero-weight taps only
        const float4 r0 = *(const float4*)(rp0 + q);
        const float4 r1 = *(const float4*)(rp1 + q);
        const float4 r2 = *(const float4*)(rp2 + q);
        const float4 r3 = *(const float4*)(rp3 + q);
        const float4 r4 = *(const float4*)(rp4 + q);
        const float4 r5 = *(const float4*)(rp5 + q);
        float4 va, vb;
        va.x = fmaf(wa0,r0.x, fmaf(wa1,r1.x, fmaf(wa2,r2.x, wa3*r3.x)));
        va.y = fmaf(wa0,r0.y, fmaf(wa1,r1.y, fmaf(wa2,r2.y, wa3*r3.y)));
        va.z = fmaf(wa0,r0.z, fmaf(wa1,r1.z, fmaf(wa2,r2.z, wa3*r3.z)));
        va.w = fmaf(wa0,r0.w, fmaf(wa1,r1.w, fmaf(wa2,r2.w, wa3*r3.w)));
        vb.x = fmaf(wb0,r2.x, fmaf(wb1,r3.x, fmaf(wb2,r4.x, wb3*r5.x)));
        vb.y = fmaf(wb0,r2.y, fmaf(wb1,r3.y, fmaf(wb2,r4.y, wb3*r5.y)));
        vb.z = fmaf(wb0,r2.z, fmaf(wb1,r3.z, fmaf(wb2,r4.z, wb3*r5.z)));
        vb.w = fmaf(wb0,r2.w, fmaf(wb1,r3.w, fmaf(wb2,r4.w, wb3*r5.w)));
        *(float4*)&xv[0][4*u] = va;
        *(float4*)&xv[1][4*u] = vb;
    }
    __builtin_amdgcn_wave_barrier();   // scheduling fence only (1 wave)

    // ---- phase 2: l-conv + horizontal 4-tap + H multiply -> xm tile ----
    // xv[mm][i] holds vert(q = qa + i); tap (col = 2n-1+b, l) at
    // i = 2*nl*31 + 31*b + l + 1 (max 558 < 560).
    const size_t hbase = ((size_t)m0*MDIM + n0)*LCH;
    for (int idx = lane; idx < 2*TNK*LCH; idx += 64) {   // 496
        const int mm = idx >= TNK*LCH;
        const int r2 = mm ? idx - TNK*LCH : idx;
        const int nl = r2 / 31;
        const int l  = r2 - nl*31;
        const int n  = n0 + nl;
        float wx0=0.125f, wx1=0.375f, wx2=0.375f, wx3=0.125f;
        if (n == 0)      wx0 = 0.f;
        if (n == MDIM-1) wx3 = 0.f;
        if (n == 0 || n == MDIM-1) {
            const float s = 1.0f/0.875f;
            wx0*=s; wx1*=s; wx2*=s; wx3*=s;
        }
        const float wb4[4] = {wx0, wx1, wx2, wx3};
        const float* xvm = xv[mm];
        const int ib = 2*nl*31 + l + 1;
        float acc = 0.f;
        #pragma unroll
        for (int b = 0; b < 4; ++b) {
            const float* q = xvm + ib + 31*b;
            float c = 0.5f*q[0];
            if (l > 0)  c += 0.25f*q[-1];
            if (l < 30) c += 0.25f*q[1];
            acc = fmaf(wb4[b], c, acc);
        }
        xm[mm][nl][l] = acc * H[hbase + (size_t)mm*(MDIM*LCH) + r2];
    }
    __builtin_amdgcn_wave_barrier();

    // ---- phase 3: diagonal partials: cl = c - n0 in [0,38), 2 halves ----
    for (int idx = lane; idx < 2*2*DIAG; idx += 64) {    // 152
        const int mm = idx >= 2*DIAG;
        const int r3 = mm ? idx - 2*DIAG : idx;
        const int h  = r3 >= DIAG;
        const int cl = h ? r3 - DIAG : r3;
        const int ilo = max(0, cl - (TNK-1));
        const int ihi = min(30, cl);
        const int mid = (ilo + ihi + 1) >> 1;
        const int lo  = h ? mid : ilo;
        const int hi  = h ? ihi : mid - 1;
        float s = 0.f;
        for (int i = lo; i <= hi; ++i)
            s += xm[mm][cl - i][i];          // stride-33 -> conflict-free
        part[(((size_t)p*NT + t)*2 + mm)*128 + h*64 + cl] = s;
    }
}

// K2_lite: yn[m][c] from tile partials (<=6 tiles x 2 halves); per-row max.
__global__ __launch_bounds__(256) void k2_lite(const float* __restrict__ part,
                                               float* __restrict__ yn,
                                               float* __restrict__ pmaxY) {
    const int m = blockIdx.x;
    const int p = m >> 1, mm = m & 1;
    float lmax = -3.4e38f;
    for (int c = threadIdx.x; c < CDIM; c += 256) {
        float s = 0.f;
        const int tlo = max(0, (c - 30) >> 3);      // ceil((c-37)/8)
        const int thi = min(NT - 1, c >> 3);
        for (int t = tlo; t <= thi; ++t) {
            const int cl = c - TNK*t;               // in [0,38)
            const float* pp = part + (((size_t)p*NT + t)*2 + mm)*128;
            s += pp[cl] + pp[64 + cl];
        }
        yn[m*CDIM + c] = s;
        lmax = fmaxf(lmax, s);
    }
    __shared__ float red[256];
    red[threadIdx.x] = lmax; __syncthreads();
    for (int s = 128; s > 0; s >>= 1) {
        if ((int)threadIdx.x < s)
            red[threadIdx.x] = fmaxf(red[threadIdx.x], red[threadIdx.x+s]);
        __syncthreads();
    }
    if (threadIdx.x == 0) pmaxY[m] = red[0];
}

// Reduce n partial maxes -> out_inv[0] = 1/max. Single block, deterministic.
__global__ __launch_bounds__(256) void kmax_reduce(const float* __restrict__ pmax,
                                                   int n,
                                                   float* __restrict__ out_inv) {
    __shared__ float red[256];
    float lmax = -3.4e38f;
    for (int i = threadIdx.x; i < n; i += 256)
        lmax = fmaxf(lmax, pmax[i]);
    red[threadIdx.x] = lmax; __syncthreads();
    for (int s = 128; s > 0; s >>= 1) {
        if ((int)threadIdx.x < s)
            red[threadIdx.x] = fmaxf(red[threadIdx.x], red[threadIdx.x+s]);
        __syncthreads();
    }
    if (threadIdx.x == 0) out_inv[0] = 1.0f / red[0];
}

// t(idx) = H[idx] * conv_i(yn/My - y at c=n+i)
__device__ __forceinline__ float t_elem(int idx,
                                        const float* __restrict__ yn,
                                        const float* __restrict__ y,
                                        const float* __restrict__ H,
                                        float inv) {
    const int i    = idx % LCH;
    const int rest = idx / LCH;
    const int n    = rest & (MDIM-1);
    const int m    = rest >> 9;
    const int c    = n + i;
    const float* ynr = yn + (size_t)m*CDIM;
    const float* yr  = y  + (size_t)m*CDIM;
    float v = 0.5f * (ynr[c]*inv - yr[c]);
    if (i > 0)     v += 0.25f*(ynr[c-1]*inv - yr[c-1]);
    if (i < LCH-1) v += 0.25f*(ynr[c+1]*inv - yr[c+1]);
    return H[idx]*v;
}

// K3: block-max of t over grid-stride range -> pmaxT[bid]. No stores of t.
__global__ __launch_bounds__(256) void k3_max(const float* __restrict__ yn,
                                              const float* __restrict__ y,
                                              const float* __restrict__ H,
                                              const float* __restrict__ scl,
                                              float* __restrict__ pmaxT) {
    const float inv = scl[0];
    float lmax = -3.4e38f;
    for (int idx = blockIdx.x*blockDim.x + threadIdx.x; idx < NELEM;
         idx += GB3*256)
        lmax = fmaxf(lmax, t_elem(idx, yn, y, H, inv));
    __shared__ float red[256];
    red[threadIdx.x] = lmax; __syncthreads();
    for (int s = 128; s > 0; s >>= 1) {
        if ((int)threadIdx.x < s)
            red[threadIdx.x] = fmaxf(red[threadIdx.x], red[threadIdx.x+s]);
        __syncthreads();
    }
    if (threadIdx.x == 0) pmaxT[blockIdx.x] = red[0];
}

// K4: recompute t, scale by 1/maxT, write out (coalesced, single pass).
__global__ __launch_bounds__(256) void k4_out(const float* __restrict__ yn,
                                              const float* __restrict__ y,
                                              const float* __restrict__ H,
                                              const float* __restrict__ scl,
                                              float* __restrict__ out) {
    const float inv  = scl[0];
    const float invT = scl[1];
    for (int idx = blockIdx.x*blockDim.x + threadIdx.x; idx < NELEM;
         idx += GB3*256)
        out[idx] = t_elem(idx, yn, y, H, inv) * invT;
}

extern "C" void kernel_launch(void* const* d_in, const int* in_sizes, int n_in,
                              void* d_out, int out_size, void* d_ws, size_t ws_size,
                              hipStream_t stream) {
    const float* X = (const float*)d_in[0];
    const float* y = (const float*)d_in[1];
    const float* H = (const float*)d_in[2];
    float* out = (float*)d_out;
    float* ws  = (float*)d_ws;

    float* part  = ws + PART_OFF;
    float* yn    = ws + YN_OFF;
    float* pmaxY = ws + PMY_OFF;
    float* pmaxT = ws + PMT_OFF;
    float* scl   = ws + SCL_OFF;   // [0]=1/maxY, [1]=1/maxT

    k1_fused<<<NPAIR*NT, 64, 0, stream>>>(X, H, part);      // 16384 blocks
    k2_lite<<<MDIM, 256, 0, stream>>>(part, yn, pmaxY);     // 512 blocks
    kmax_reduce<<<1, 256, 0, stream>>>(pmaxY, MDIM, scl);
    k3_max<<<GB3, 256, 0, stream>>>(yn, y, H, scl, pmaxT);
    kmax_reduce<<<1, 256, 0, stream>>>(pmaxT, GB3, scl + 1);
    k4_out<<<GB3, 256, 0, stream>>>(yn, y, H, scl, out);
}

// Round 18
// 89.973 us; speedup vs baseline: 1.1363x; 1.1363x over previous
//
#include <hip/hip_runtime.h>

#define MDIM 512
#define LCH  31
#define CDIM 542   // MD + L - 1
#define INW  1024
#define RS   (INW*LCH)          // floats per input row = 31744
#define NELEM (MDIM*MDIM*LCH)   // 8126464
#define GB3  2048               // k3/k4 grid blocks

#define TNK  16                 // output n-cols per k1 tile
#define NT   32                 // tiles per row (512/16)
#define NPAIR 256               // m-pairs
#define SEGF 1056               // staged floats per sub-tile (33 cols x 31 + pad)
#define NF4  264                // float4s per sub-tile
#define DIAG 46                 // distinct c per tile: TNK + LCH - 1

// ws layout (floats): part[pair][tile][mm][128], yn, pmaxY[512], pmaxT[GB3], scl[2]
#define PART_OFF 0
#define PART_SZ  (NPAIR*NT*2*128)        // 2097152
#define YN_OFF   (PART_OFF + PART_SZ)
#define PMY_OFF  (YN_OFF + MDIM*CDIM)
#define PMT_OFF  (PMY_OFF + MDIM)
#define SCL_OFF  (PMT_OFF + GB3)

typedef float f32x4 __attribute__((ext_vector_type(4)));

// Issue 6 independent 16-B global loads back-to-back, wait inside the block.
// Six distinct early-clobber dest tuples force the register allocator to
// keep all 6 loads in flight (the compiler re-serialized register-staged
// loads to ~2-in-flight at VGPR<=40 in r5/r6/r8/r12/r16 — this is the
// minimal-safe AITER-style fix: waits handled inside; consumers data-depend
// on the outputs so no hoisting hazard).
__device__ __forceinline__ void load6(const float* a0, const float* a1,
                                      const float* a2, const float* a3,
                                      const float* a4, const float* a5,
                                      f32x4& r0, f32x4& r1, f32x4& r2,
                                      f32x4& r3, f32x4& r4, f32x4& r5) {
    asm volatile(
        "global_load_dwordx4 %0, %6, off\n\t"
        "global_load_dwordx4 %1, %7, off\n\t"
        "global_load_dwordx4 %2, %8, off\n\t"
        "global_load_dwordx4 %3, %9, off\n\t"
        "global_load_dwordx4 %4, %10, off\n\t"
        "global_load_dwordx4 %5, %11, off\n\t"
        "s_waitcnt vmcnt(0)"
        : "=&v"(r0), "=&v"(r1), "=&v"(r2), "=&v"(r3), "=&v"(r4), "=&v"(r5)
        : "v"(a0), "v"(a1), "v"(a2), "v"(a3), "v"(a4), "v"(a5)
        : "memory");
}

// K1: r16 geometry (best measured), phase-1 loads via inline-asm burst.
// Block = (m-pair p, n-tile of 16), 12.7 KB LDS. Clamped values only meet
// zero weights:
//   col -1 / 1024 -> wx0/wx3 = 0 at n = 0/511
//   row -1 / 1024 -> wa0/wb3 = 0 at m = 0/511
__global__ __launch_bounds__(256) void k1_fused(const float* __restrict__ X,
                                                const float* __restrict__ H,
                                                float* __restrict__ part) {
    __shared__ float xv[2][SEGF];     // 8.4 KB vertically-resized tiles
    __shared__ float xm[2][TNK][33];  // 4.3 KB H*conv tiles, padded

    const int bid = blockIdx.x;
    const int t   = bid & (NT-1);
    const int p   = bid >> 5;
    const int n0  = t * TNK;
    const int m0  = 2*p;
    const int tid = threadIdx.x;
    const int qa  = 992*t - 32;       // float4-aligned staged-q origin

    const float* rp0 = X + (size_t)max(4*p - 1, 0) * RS;
    const float* rp1 = X + (size_t)(4*p    ) * RS;
    const float* rp2 = X + (size_t)(4*p + 1) * RS;
    const float* rp3 = X + (size_t)(4*p + 2) * RS;
    const float* rp4 = X + (size_t)(4*p + 3) * RS;
    const float* rp5 = X + (size_t)min(4*p + 4, INW-1) * RS;

    float wa0=0.125f, wa1=0.375f, wa2=0.375f, wa3=0.125f;   // m = m0
    if (m0 == 0) {
        const float s = 1.0f/0.875f;
        wa0 = 0.f; wa1 = 0.375f*s; wa2 = 0.375f*s; wa3 = 0.125f*s;
    }
    float wb0=0.125f, wb1=0.375f, wb2=0.375f, wb3=0.125f;   // m = m0+1
    if (m0 + 1 == MDIM-1) {
        const float s = 1.0f/0.875f;
        wb0 = 0.125f*s; wb1 = 0.375f*s; wb2 = 0.375f*s; wb3 = 0.f;
    }

    // ---- phase 1: 6-row asm load burst, vertical 4-tap for both m ----
    for (int u = tid; u < NF4; u += 256) {
        int q = qa + 4*u;
        q = min(max(q, 0), RS - 4);   // clamp -> zero-weight taps only
        f32x4 r0, r1, r2, r3, r4, r5;
        load6(rp0 + q, rp1 + q, rp2 + q, rp3 + q, rp4 + q, rp5 + q,
              r0, r1, r2, r3, r4, r5);
        f32x4 va, vb;
        #pragma unroll
        for (int e = 0; e < 4; ++e) {
            va[e] = fmaf(wa0,r0[e], fmaf(wa1,r1[e], fmaf(wa2,r2[e], wa3*r3[e])));
            vb[e] = fmaf(wb0,r2[e], fmaf(wb1,r3[e], fmaf(wb2,r4[e], wb3*r5[e])));
        }
        *(f32x4*)&xv[0][4*u] = va;
        *(f32x4*)&xv[1][4*u] = vb;
    }
    __syncthreads();

    // ---- phase 2: l-conv + horizontal 4-tap + H multiply -> xm tile ----
    // xv[mm][i] holds vert(q = qa + i); tap (col = 2n-1+b, l) at
    // i = 2*nl*31 + 31*b + l + 1 (max 1054 < 1056).
    const size_t hbase = ((size_t)m0*MDIM + n0)*LCH;
    for (int idx = tid; idx < 2*TNK*LCH; idx += 256) {   // 992
        const int mm = idx >= TNK*LCH;
        const int r2 = mm ? idx - TNK*LCH : idx;
        const int nl = r2 / 31;
        const int l  = r2 - nl*31;
        const int n  = n0 + nl;
        float wx0=0.125f, wx1=0.375f, wx2=0.375f, wx3=0.125f;
        if (n == 0)      wx0 = 0.f;
        if (n == MDIM-1) wx3 = 0.f;
        if (n == 0 || n == MDIM-1) {
            const float s = 1.0f/0.875f;
            wx0*=s; wx1*=s; wx2*=s; wx3*=s;
        }
        const float wb4[4] = {wx0, wx1, wx2, wx3};
        const float* xvm = xv[mm];
        const int ib = 2*nl*31 + l + 1;
        float acc = 0.f;
        #pragma unroll
        for (int b = 0; b < 4; ++b) {
            const float* q = xvm + ib + 31*b;
            float c = 0.5f*q[0];
            if (l > 0)  c += 0.25f*q[-1];
            if (l < 30) c += 0.25f*q[1];
            acc = fmaf(wb4[b], c, acc);
        }
        xm[mm][nl][l] = acc * H[hbase + (size_t)mm*(MDIM*LCH) + r2];
    }
    __syncthreads();

    // ---- phase 3: diagonal partials: cl = c - n0 in [0,46), 2 halves ----
    if (tid < 2*2*DIAG) {                 // 184
        const int mm = tid >= 2*DIAG;
        const int r3 = mm ? tid - 2*DIAG : tid;
        const int h  = r3 >= DIAG;
        const int cl = h ? r3 - DIAG : r3;
        const int ilo = max(0, cl - (TNK-1));
        const int ihi = min(30, cl);
        const int mid = (ilo + ihi + 1) >> 1;
        const int lo  = h ? mid : ilo;
        const int hi  = h ? ihi : mid - 1;
        float s = 0.f;
        for (int i = lo; i <= hi; ++i)
            s += xm[mm][cl - i][i];          // stride-33 -> conflict-free
        part[(((size_t)p*NT + t)*2 + mm)*128 + h*64 + cl] = s;
    }
}

// K2_lite: yn[m][c] from tile partials (<=3 tiles x 2 halves); per-row max.
__global__ __launch_bounds__(256) void k2_lite(const float* __restrict__ part,
                                               float* __restrict__ yn,
                                               float* __restrict__ pmaxY) {
    const int m = blockIdx.x;
    const int p = m >> 1, mm = m & 1;
    float lmax = -3.4e38f;
    for (int c = threadIdx.x; c < CDIM; c += 256) {
        float s = 0.f;
        const int tlo = max(0, (c - 30) >> 4);      // ceil((c-45)/16)
        const int thi = min(NT - 1, c >> 4);
        for (int t = tlo; t <= thi; ++t) {
            const int cl = c - TNK*t;               // in [0,46)
            const float* pp = part + (((size_t)p*NT + t)*2 + mm)*128;
            s += pp[cl] + pp[64 + cl];
        }
        yn[m*CDIM + c] = s;
        lmax = fmaxf(lmax, s);
    }
    __shared__ float red[256];
    red[threadIdx.x] = lmax; __syncthreads();
    for (int s = 128; s > 0; s >>= 1) {
        if ((int)threadIdx.x < s)
            red[threadIdx.x] = fmaxf(red[threadIdx.x], red[threadIdx.x+s]);
        __syncthreads();
    }
    if (threadIdx.x == 0) pmaxY[m] = red[0];
}

// Reduce n partial maxes -> out_inv[0] = 1/max. Single block, deterministic.
__global__ __launch_bounds__(256) void kmax_reduce(const float* __restrict__ pmax,
                                                   int n,
                                                   float* __restrict__ out_inv) {
    __shared__ float red[256];
    float lmax = -3.4e38f;
    for (int i = threadIdx.x; i < n; i += 256)
        lmax = fmaxf(lmax, pmax[i]);
    red[threadIdx.x] = lmax; __syncthreads();
    for (int s = 128; s > 0; s >>= 1) {
        if ((int)threadIdx.x < s)
            red[threadIdx.x] = fmaxf(red[threadIdx.x], red[threadIdx.x+s]);
        __syncthreads();
    }
    if (threadIdx.x == 0) out_inv[0] = 1.0f / red[0];
}

// t(idx) = H[idx] * conv_i(yn/My - y at c=n+i)
__device__ __forceinline__ float t_elem(int idx,
                                        const float* __restrict__ yn,
                                        const float* __restrict__ y,
                                        const float* __restrict__ H,
                                        float inv) {
    const int i    = idx % LCH;
    const int rest = idx / LCH;
    const int n    = rest & (MDIM-1);
    const int m    = rest >> 9;
    const int c    = n + i;
    const float* ynr = yn + (size_t)m*CDIM;
    const float* yr  = y  + (size_t)m*CDIM;
    float v = 0.5f * (ynr[c]*inv - yr[c]);
    if (i > 0)     v += 0.25f*(ynr[c-1]*inv - yr[c-1]);
    if (i < LCH-1) v += 0.25f*(ynr[c+1]*inv - yr[c+1]);
    return H[idx]*v;
}

// K3: block-max of t over grid-stride range -> pmaxT[bid]. No stores of t.
__global__ __launch_bounds__(256) void k3_max(const float* __restrict__ yn,
                                              const float* __restrict__ y,
                                              const float* __restrict__ H,
                                              const float* __restrict__ scl,
                                              float* __restrict__ pmaxT) {
    const float inv = scl[0];
    float lmax = -3.4e38f;
    for (int idx = blockIdx.x*blockDim.x + threadIdx.x; idx < NELEM;
         idx += GB3*256)
        lmax = fmaxf(lmax, t_elem(idx, yn, y, H, inv));
    __shared__ float red[256];
    red[threadIdx.x] = lmax; __syncthreads();
    for (int s = 128; s > 0; s >>= 1) {
        if ((int)threadIdx.x < s)
            red[threadIdx.x] = fmaxf(red[threadIdx.x], red[threadIdx.x+s]);
        __syncthreads();
    }
    if (threadIdx.x == 0) pmaxT[blockIdx.x] = red[0];
}

// K4: recompute t, scale by 1/maxT, write out (coalesced, single pass).
__global__ __launch_bounds__(256) void k4_out(const float* __restrict__ yn,
                                              const float* __restrict__ y,
                                              const float* __restrict__ H,
                                              const float* __restrict__ scl,
                                              float* __restrict__ out) {
    const float inv  = scl[0];
    const float invT = scl[1];
    for (int idx = blockIdx.x*blockDim.x + threadIdx.x; idx < NELEM;
         idx += GB3*256)
        out[idx] = t_elem(idx, yn, y, H, inv) * invT;
}

extern "C" void kernel_launch(void* const* d_in, const int* in_sizes, int n_in,
                              void* d_out, int out_size, void* d_ws, size_t ws_size,
                              hipStream_t stream) {
    const float* X = (const float*)d_in[0];
    const float* y = (const float*)d_in[1];
    const float* H = (const float*)d_in[2];
    float* out = (float*)d_out;
    float* ws  = (float*)d_ws;

    float* part  = ws + PART_OFF;
    float* yn    = ws + YN_OFF;
    float* pmaxY = ws + PMY_OFF;
    float* pmaxT = ws + PMT_OFF;
    float* scl   = ws + SCL_OFF;   // [0]=1/maxY, [1]=1/maxT

    k1_fused<<<NPAIR*NT, 256, 0, stream>>>(X, H, part);     // 8192 blocks
    k2_lite<<<MDIM, 256, 0, stream>>>(part, yn, pmaxY);     // 512 blocks
    kmax_reduce<<<1, 256, 0, stream>>>(pmaxY, MDIM, scl);
    k3_max<<<GB3, 256, 0, stream>>>(yn, y, H, scl, pmaxT);
    kmax_reduce<<<1, 256, 0, stream>>>(pmaxT, GB3, scl + 1);
    k4_out<<<GB3, 256, 0, stream>>>(yn, y, H, scl, out);
}

// Round 19
// 87.323 us; speedup vs baseline: 1.1708x; 1.0303x over previous
//
#include <hip/hip_runtime.h>

#define MDIM 512
#define LCH  31
#define CDIM 542   // MD + L - 1
#define INW  1024
#define RS   (INW*LCH)          // floats per input row = 31744
#define NELEM (MDIM*MDIM*LCH)   // 8126464
#define GB3  2048               // k3/k4 grid blocks

#define TNK  16                 // output n-cols per k1 tile
#define NT   32                 // tiles per row (512/16)
#define NPAIR 256               // m-pairs
#define SEGF 1056               // staged floats per sub-tile (33 cols x 31 + pad)
#define NF4  264                // float4s per sub-tile
#define DIAG 46                 // distinct c per tile: TNK + LCH - 1

// ws layout (floats): part[pair][tile][mm][128], yn, pmaxY[512], pmaxT[GB3], scl[2]
#define PART_OFF 0
#define PART_SZ  (NPAIR*NT*2*128)        // 2097152
#define YN_OFF   (PART_OFF + PART_SZ)
#define PMY_OFF  (YN_OFF + MDIM*CDIM)
#define PMT_OFF  (PMY_OFF + MDIM)
#define SCL_OFF  (PMT_OFF + GB3)

// K1 (r16-exact, best measured k1 ~68us / total 86.7us): fused bilinear
// resize + l-conv + H-mult + CASSI diagonal partials. Block = (m-pair p,
// n-tile of 16), 12.7 KB LDS -> 8 blocks/CU (wave-capped). Ten structural
// variants (r9-r18) land k1 at 68-77us with no saturated counter: this is
// an L3-resident-access latency floor (~4.3-4.6 TB/s touch-rate), and this
// geometry is its minimum. Clamped values only meet zero weights:
//   col -1 / 1024 -> wx0/wx3 = 0 at n = 0/511
//   row -1 / 1024 -> wa0/wb3 = 0 at m = 0/511
__global__ __launch_bounds__(256) void k1_fused(const float* __restrict__ X,
                                                const float* __restrict__ H,
                                                float* __restrict__ part) {
    __shared__ float xv[2][SEGF];     // 8.4 KB vertically-resized tiles
    __shared__ float xm[2][TNK][33];  // 4.3 KB H*conv tiles, padded

    const int bid = blockIdx.x;
    const int t   = bid & (NT-1);
    const int p   = bid >> 5;
    const int n0  = t * TNK;
    const int m0  = 2*p;
    const int tid = threadIdx.x;
    const int qa  = 992*t - 32;       // float4-aligned staged-q origin

    const float* rp0 = X + (size_t)max(4*p - 1, 0) * RS;
    const float* rp1 = X + (size_t)(4*p    ) * RS;
    const float* rp2 = X + (size_t)(4*p + 1) * RS;
    const float* rp3 = X + (size_t)(4*p + 2) * RS;
    const float* rp4 = X + (size_t)(4*p + 3) * RS;
    const float* rp5 = X + (size_t)min(4*p + 4, INW-1) * RS;

    float wa0=0.125f, wa1=0.375f, wa2=0.375f, wa3=0.125f;   // m = m0
    if (m0 == 0) {
        const float s = 1.0f/0.875f;
        wa0 = 0.f; wa1 = 0.375f*s; wa2 = 0.375f*s; wa3 = 0.125f*s;
    }
    float wb0=0.125f, wb1=0.375f, wb2=0.375f, wb3=0.125f;   // m = m0+1
    if (m0 + 1 == MDIM-1) {
        const float s = 1.0f/0.875f;
        wb0 = 0.125f*s; wb1 = 0.375f*s; wb2 = 0.375f*s; wb3 = 0.f;
    }

    // ---- phase 1: 6-row streams, vertical 4-tap for both m ----
    for (int u = tid; u < NF4; u += 256) {
        int q = qa + 4*u;
        q = min(max(q, 0), RS - 4);   // clamp -> zero-weight taps only
        const float4 r0 = *(const float4*)(rp0 + q);
        const float4 r1 = *(const float4*)(rp1 + q);
        const float4 r2 = *(const float4*)(rp2 + q);
        const float4 r3 = *(const float4*)(rp3 + q);
        const float4 r4 = *(const float4*)(rp4 + q);
        const float4 r5 = *(const float4*)(rp5 + q);
        float4 va, vb;
        va.x = fmaf(wa0,r0.x, fmaf(wa1,r1.x, fmaf(wa2,r2.x, wa3*r3.x)));
        va.y = fmaf(wa0,r0.y, fmaf(wa1,r1.y, fmaf(wa2,r2.y, wa3*r3.y)));
        va.z = fmaf(wa0,r0.z, fmaf(wa1,r1.z, fmaf(wa2,r2.z, wa3*r3.z)));
        va.w = fmaf(wa0,r0.w, fmaf(wa1,r1.w, fmaf(wa2,r2.w, wa3*r3.w)));
        vb.x = fmaf(wb0,r2.x, fmaf(wb1,r3.x, fmaf(wb2,r4.x, wb3*r5.x)));
        vb.y = fmaf(wb0,r2.y, fmaf(wb1,r3.y, fmaf(wb2,r4.y, wb3*r5.y)));
        vb.z = fmaf(wb0,r2.z, fmaf(wb1,r3.z, fmaf(wb2,r4.z, wb3*r5.z)));
        vb.w = fmaf(wb0,r2.w, fmaf(wb1,r3.w, fmaf(wb2,r4.w, wb3*r5.w)));
        *(float4*)&xv[0][4*u] = va;
        *(float4*)&xv[1][4*u] = vb;
    }
    __syncthreads();

    // ---- phase 2: l-conv + horizontal 4-tap + H multiply -> xm tile ----
    // xv[mm][i] holds vert(q = qa + i); tap (col = 2n-1+b, l) at
    // i = 2*nl*31 + 31*b + l + 1 (max 1054 < 1056).
    const size_t hbase = ((size_t)m0*MDIM + n0)*LCH;
    for (int idx = tid; idx < 2*TNK*LCH; idx += 256) {   // 992
        const int mm = idx >= TNK*LCH;
        const int r2 = mm ? idx - TNK*LCH : idx;
        const int nl = r2 / 31;
        const int l  = r2 - nl*31;
        const int n  = n0 + nl;
        float wx0=0.125f, wx1=0.375f, wx2=0.375f, wx3=0.125f;
        if (n == 0)      wx0 = 0.f;
        if (n == MDIM-1) wx3 = 0.f;
        if (n == 0 || n == MDIM-1) {
            const float s = 1.0f/0.875f;
            wx0*=s; wx1*=s; wx2*=s; wx3*=s;
        }
        const float wb4[4] = {wx0, wx1, wx2, wx3};
        const float* xvm = xv[mm];
        const int ib = 2*nl*31 + l + 1;
        float acc = 0.f;
        #pragma unroll
        for (int b = 0; b < 4; ++b) {
            const float* q = xvm + ib + 31*b;
            float c = 0.5f*q[0];
            if (l > 0)  c += 0.25f*q[-1];
            if (l < 30) c += 0.25f*q[1];
            acc = fmaf(wb4[b], c, acc);
        }
        xm[mm][nl][l] = acc * H[hbase + (size_t)mm*(MDIM*LCH) + r2];
    }
    __syncthreads();

    // ---- phase 3: diagonal partials: cl = c - n0 in [0,46), 2 halves ----
    if (tid < 2*2*DIAG) {                 // 184
        const int mm = tid >= 2*DIAG;
        const int r3 = mm ? tid - 2*DIAG : tid;
        const int h  = r3 >= DIAG;
        const int cl = h ? r3 - DIAG : r3;
        const int ilo = max(0, cl - (TNK-1));
        const int ihi = min(30, cl);
        const int mid = (ilo + ihi + 1) >> 1;
        const int lo  = h ? mid : ilo;
        const int hi  = h ? ihi : mid - 1;
        float s = 0.f;
        for (int i = lo; i <= hi; ++i)
            s += xm[mm][cl - i][i];          // stride-33 -> conflict-free
        part[(((size_t)p*NT + t)*2 + mm)*128 + h*64 + cl] = s;
    }
}

// K2_lite: yn[m][c] from tile partials (<=3 tiles x 2 halves); per-row max.
__global__ __launch_bounds__(256) void k2_lite(const float* __restrict__ part,
                                               float* __restrict__ yn,
                                               float* __restrict__ pmaxY) {
    const int m = blockIdx.x;
    const int p = m >> 1, mm = m & 1;
    float lmax = -3.4e38f;
    for (int c = threadIdx.x; c < CDIM; c += 256) {
        float s = 0.f;
        const int tlo = max(0, (c - 30) >> 4);      // ceil((c-45)/16)
        const int thi = min(NT - 1, c >> 4);
        for (int t = tlo; t <= thi; ++t) {
            const int cl = c - TNK*t;               // in [0,46)
            const float* pp = part + (((size_t)p*NT + t)*2 + mm)*128;
            s += pp[cl] + pp[64 + cl];
        }
        yn[m*CDIM + c] = s;
        lmax = fmaxf(lmax, s);
    }
    __shared__ float red[256];
    red[threadIdx.x] = lmax; __syncthreads();
    for (int s = 128; s > 0; s >>= 1) {
        if ((int)threadIdx.x < s)
            red[threadIdx.x] = fmaxf(red[threadIdx.x], red[threadIdx.x+s]);
        __syncthreads();
    }
    if (threadIdx.x == 0) pmaxY[m] = red[0];
}

// Reduce n partial maxes -> out_inv[0] = 1/max. Single block, deterministic.
__global__ __launch_bounds__(256) void kmax_reduce(const float* __restrict__ pmax,
                                                   int n,
                                                   float* __restrict__ out_inv) {
    __shared__ float red[256];
    float lmax = -3.4e38f;
    for (int i = threadIdx.x; i < n; i += 256)
        lmax = fmaxf(lmax, pmax[i]);
    red[threadIdx.x] = lmax; __syncthreads();
    for (int s = 128; s > 0; s >>= 1) {
        if ((int)threadIdx.x < s)
            red[threadIdx.x] = fmaxf(red[threadIdx.x], red[threadIdx.x+s]);
        __syncthreads();
    }
    if (threadIdx.x == 0) out_inv[0] = 1.0f / red[0];
}

// t(idx) = H[idx] * conv_i(yn/My - y at c=n+i)
__device__ __forceinline__ float t_elem(int idx,
                                        const float* __restrict__ yn,
                                        const float* __restrict__ y,
                                        const float* __restrict__ H,
                                        float inv) {
    const int i    = idx % LCH;
    const int rest = idx / LCH;
    const int n    = rest & (MDIM-1);
    const int m    = rest >> 9;
    const int c    = n + i;
    const float* ynr = yn + (size_t)m*CDIM;
    const float* yr  = y  + (size_t)m*CDIM;
    float v = 0.5f * (ynr[c]*inv - yr[c]);
    if (i > 0)     v += 0.25f*(ynr[c-1]*inv - yr[c-1]);
    if (i < LCH-1) v += 0.25f*(ynr[c+1]*inv - yr[c+1]);
    return H[idx]*v;
}

// K3: block-max of t over grid-stride range -> pmaxT[bid]. No stores of t.
__global__ __launch_bounds__(256) void k3_max(const float* __restrict__ yn,
                                              const float* __restrict__ y,
                                              const float* __restrict__ H,
                                              const float* __restrict__ scl,
                                              float* __restrict__ pmaxT) {
    const float inv = scl[0];
    float lmax = -3.4e38f;
    for (int idx = blockIdx.x*blockDim.x + threadIdx.x; idx < NELEM;
         idx += GB3*256)
        lmax = fmaxf(lmax, t_elem(idx, yn, y, H, inv));
    __shared__ float red[256];
    red[threadIdx.x] = lmax; __syncthreads();
    for (int s = 128; s > 0; s >>= 1) {
        if ((int)threadIdx.x < s)
            red[threadIdx.x] = fmaxf(red[threadIdx.x], red[threadIdx.x+s]);
        __syncthreads();
    }
    if (threadIdx.x == 0) pmaxT[blockIdx.x] = red[0];
}

// K4: recompute t, scale by 1/maxT, write out (coalesced, single pass).
__global__ __launch_bounds__(256) void k4_out(const float* __restrict__ yn,
                                              const float* __restrict__ y,
                                              const float* __restrict__ H,
                                              const float* __restrict__ scl,
                                              float* __restrict__ out) {
    const float inv  = scl[0];
    const float invT = scl[1];
    for (int idx = blockIdx.x*blockDim.x + threadIdx.x; idx < NELEM;
         idx += GB3*256)
        out[idx] = t_elem(idx, yn, y, H, inv) * invT;
}

extern "C" void kernel_launch(void* const* d_in, const int* in_sizes, int n_in,
                              void* d_out, int out_size, void* d_ws, size_t ws_size,
                              hipStream_t stream) {
    const float* X = (const float*)d_in[0];
    const float* y = (const float*)d_in[1];
    const float* H = (const float*)d_in[2];
    float* out = (float*)d_out;
    float* ws  = (float*)d_ws;

    float* part  = ws + PART_OFF;
    float* yn    = ws + YN_OFF;
    float* pmaxY = ws + PMY_OFF;
    float* pmaxT = ws + PMT_OFF;
    float* scl   = ws + SCL_OFF;   // [0]=1/maxY, [1]=1/maxT

    k1_fused<<<NPAIR*NT, 256, 0, stream>>>(X, H, part);     // 8192 blocks
    k2_lite<<<MDIM, 256, 0, stream>>>(part, yn, pmaxY);     // 512 blocks
    kmax_reduce<<<1, 256, 0, stream>>>(pmaxY, MDIM, scl);
    k3_max<<<GB3, 256, 0, stream>>>(yn, y, H, scl, pmaxT);
    kmax_reduce<<<1, 256, 0, stream>>>(pmaxT, GB3, scl + 1);
    k4_out<<<GB3, 256, 0, stream>>>(yn, y, H, scl, out);
}